// Round 18
// baseline (169.258 us; speedup 1.0000x reference)
//
#include <hip/hip_runtime.h>
#include <hip/hip_bf16.h>

// Problem constants (from reference)
#define BATCH   8
#define MROWS   2048      // C*P per batch
#define MTOT    16384     // BATCH*MROWS
#define DIM_Z   512
#define DIM_G   1024
#define EDIM    128
#define EPS     1e-6f
#define BK      64        // K-step

typedef unsigned short u16;
typedef unsigned int   u32;
typedef __attribute__((ext_vector_type(8))) short bf16x8;
typedef __attribute__((ext_vector_type(4))) float f32x4;

// f32 -> bf16 round-to-nearest-even (bit trick; inputs are finite)
__device__ __forceinline__ u16 f2b(float f) {
    u32 x = __float_as_uint(f);
    u32 r = x + 0x7fffu + ((x >> 16) & 1u);
    return (u16)(r >> 16);
}

// packed f32 pair -> 2x bf16 in one u32 (RNE), single VALU inst on gfx950
__device__ __forceinline__ u32 cvtpk(float lo, float hi) {
    u32 r;
    asm("v_cvt_pk_bf16_f32 %0, %1, %2" : "=v"(r) : "v"(lo), "v"(hi));
    return r;
}

// async global->LDS, 16B per lane, dest = wave-uniform base + lane*16
#define GLD16(gsrc, ldst) __builtin_amdgcn_global_load_lds( \
    (const __attribute__((address_space(1))) unsigned int*)(gsrc), \
    (__attribute__((address_space(3))) unsigned int*)(ldst), 16, 0, 0)

// ---- kernel 1: u/v projections; zero rsum and done flags ----
__global__ void uv_kernel(const float* __restrict__ emb, const int* __restrict__ idx,
                          const float* __restrict__ Wu, const float* __restrict__ Wv,
                          float* __restrict__ u, float* __restrict__ v,
                          float* __restrict__ rsum, u32* __restrict__ done) {
    __shared__ float a[EDIM];
    int b = blockIdx.y;
    int t = threadIdx.x;
    if (blockIdx.x == 0) {  // zero rsum slice + done flags for batch b
        for (int i = t; i < MROWS; i += 256) rsum[(size_t)b * MROWS + i] = 0.f;
        if (t < 16) done[b * 16 + t] = 0;
    }
    if (t < EDIM) a[t] = emb[(size_t)idx[b] * EDIM + t];
    __syncthreads();
    int tx = t & 31, ty = t >> 5;
    int oBase = blockIdx.x * 256;
    for (int o0 = 0; o0 < 256; o0 += 8) {
        int o = oBase + o0 + ty;
        const float* wrow = (o < DIM_G) ? (Wu + (size_t)o * EDIM)
                                        : (Wv + (size_t)(o - DIM_G) * EDIM);
        float s = 0.f;
#pragma unroll
        for (int q = 0; q < 4; ++q) s += a[q * 32 + tx] * wrow[q * 32 + tx];
        s += __shfl_xor(s, 1, 64);
        s += __shfl_xor(s, 2, 64);
        s += __shfl_xor(s, 4, 64);
        s += __shfl_xor(s, 8, 64);
        s += __shfl_xor(s, 16, 64);
        if (tx == 0) {
            if (o < DIM_G) u[b * DIM_G + o] = s;
            else           v[b * DIM_Z + (o - DIM_G)] = s;
        }
    }
}

// -- kernel 2: W[b,g,d] = W_base + u*v -> bf16 (+ transposed WT), b = h&7 --
__global__ void wpack_kernel(const float* __restrict__ Wbase,
                             const float* __restrict__ u, const float* __restrict__ v,
                             u16* __restrict__ W, u16* __restrict__ WT) {
    __shared__ u16 tile[32][33];
    int h = blockIdx.x;
    int b = h & 7, t8 = h >> 3;          // t8 in [0,512)
    int d0 = (t8 & 15) * 32, g0 = (t8 >> 4) * 32;
    int tx = threadIdx.x, ty = threadIdx.y;
    float vb = v[b * DIM_Z + d0 + tx];
#pragma unroll
    for (int j = 0; j < 4; ++j) {
        int g = g0 + ty + j * 8;
        u16 h16 = f2b(Wbase[(size_t)g * DIM_Z + d0 + tx] + u[b * DIM_G + g] * vb);
        W[((size_t)b * DIM_G + g) * DIM_Z + d0 + tx] = h16;
        tile[ty + j * 8][tx] = h16;
    }
    __syncthreads();
#pragma unroll
    for (int j = 0; j < 4; ++j)
        WT[((size_t)b * DIM_Z + d0 + ty + j * 8) * DIM_G + g0 + tx] =
            tile[tx][ty + j * 8];
}

// ============ FUSED producer-consumer GEMM (one persistent kernel) ============
// Grid 512 = 64 blocks/XCD (xcd = h&7), all co-resident (LB(256,2): VGPR<=256
// -> >=2 blocks/CU -> 512 resident before any spin; produce-before-consume ->
// deadlock-free). Block j (per XCD): mT = j>>2, q = j&3.
//   PRODUCE: gemm1 fat tile 128m x 256n (r17 champion): A = qz f32 fused
//     (issue-early f32 loads, v_cvt_pk, swizzled ds_write), B = W[b] gld_lds;
//     epilogue relu -> qg (normal store, L2-local) + rsum atomics. Then
//     __threadfence + __syncthreads + RELEASE atomicAdd(done[xcd][mT]).
//   CONSUME: gemm2 tile 128m x 128d (same mT strip! q = d-slice) after
//     ACQUIRE-spin for done[xcd][mT]==4 (own tile counts -> waits for 3
//     lockstep siblings). Same-XCD producer/consumer -> L2-coherent + hot.
__global__ __launch_bounds__(256, 2)
void gemm_fused(const float* __restrict__ qz, const u16* __restrict__ Wall,
                const u16* __restrict__ WTall, u16* __restrict__ qg,
                float* __restrict__ rsum, float* __restrict__ out,
                u32* __restrict__ done) {
    __shared__ u16 As[128 * BK];   // 16 KB
    __shared__ u16 Bs[256 * BK];   // 32 KB (consume phase uses first 16 KB)

    int h = blockIdx.x;
    int xcd = h & 7, j = h >> 3;              // j in [0,64)
    int mT = j >> 2, q = j & 3;
    int b = xcd;
    int mBase = (xcd * 16 + mT) * 128;

    int tid  = threadIdx.x;
    int lane = tid & 63, wid = tid >> 6;
    int wm = wid >> 1, wn = wid & 1;
    int lr = lane & 15, lg = lane >> 4;

    int sRow = tid >> 3;                      // 0..31
    int sC   = tid & 7;
    int cw   = sC ^ (sRow & 7);

    // ---------------- PRODUCE: gemm1 fat 128x256 ----------------
    {
        const int N = DIM_G, K = DIM_Z;
        int nBase = q * 256;
        f32x4 acc[4][8] = {};
        const float* aSrc = qz + (size_t)(mBase + sRow) * K + sC * 8;
        const u16*   bSrc = Wall + (size_t)b * DIM_G * DIM_Z
                                 + (size_t)(nBase + sRow) * K + cw * 8;

        for (int kt = 0; kt < K; kt += BK) {
            float4 alo[4], ahi[4];
#pragma unroll
            for (int r = 0; r < 4; ++r) {     // issue-early: no LDS hazard
                const float* g = aSrc + (size_t)r * 32 * K + kt;
                alo[r] = *(const float4*)g;
                ahi[r] = *(const float4*)(g + 4);
            }
            __syncthreads();
#pragma unroll
            for (int r = 0; r < 8; ++r)       // B: 256 rows
                GLD16(bSrc + (size_t)r * 32 * K + kt, &Bs[(r * 256 + wid * 64) * 8]);
#pragma unroll
            for (int r = 0; r < 4; ++r) {     // packed cvt + swizzled ds_write
                uint4 qv;
                qv.x = cvtpk(alo[r].x, alo[r].y);
                qv.y = cvtpk(alo[r].z, alo[r].w);
                qv.z = cvtpk(ahi[r].x, ahi[r].y);
                qv.w = cvtpk(ahi[r].z, ahi[r].w);
                *(uint4*)&As[(r * 32 + sRow) * BK + cw * 8] = qv;
            }
            __syncthreads();
#pragma unroll
            for (int ks = 0; ks < 2; ++ks) {
                bf16x8 af[4], bfr[8];
#pragma unroll
                for (int mi = 0; mi < 4; ++mi) {
                    int row = wm * 64 + mi * 16 + lr;
                    int cq  = (ks * 4 + lg) ^ (row & 7);
                    af[mi] = *(const bf16x8*)&As[row * BK + cq * 8];
                }
#pragma unroll
                for (int ni = 0; ni < 8; ++ni) {
                    int row = wn * 128 + ni * 16 + lr;
                    int cq  = (ks * 4 + lg) ^ (row & 7);
                    bfr[ni] = *(const bf16x8*)&Bs[row * BK + cq * 8];
                }
                __builtin_amdgcn_s_setprio(1);
#pragma unroll
                for (int mi = 0; mi < 4; ++mi)
#pragma unroll
                    for (int ni = 0; ni < 8; ++ni)
                        acc[mi][ni] = __builtin_amdgcn_mfma_f32_16x16x32_bf16(
                            af[mi], bfr[ni], acc[mi][ni], 0, 0, 0);
                __builtin_amdgcn_s_setprio(0);
            }
        }

        int mw = mBase + wm * 64, nw = q * 256 + wn * 128;
#pragma unroll
        for (int mi = 0; mi < 4; ++mi)
#pragma unroll
            for (int r = 0; r < 4; ++r) {
                int m = mw + mi * 16 + lg * 4 + r;
                float vals[8];
                float s = 0.f;
#pragma unroll
                for (int ni = 0; ni < 8; ++ni) {
                    vals[ni] = fmaxf(acc[mi][ni][r], 0.f);
                    s += vals[ni];
                }
#pragma unroll
                for (int ni = 0; ni < 8; ++ni)
                    qg[(size_t)m * N + nw + ni * 16 + lr] = f2b(vals[ni]);
                s += __shfl_xor(s, 1, 64);
                s += __shfl_xor(s, 2, 64);
                s += __shfl_xor(s, 4, 64);
                s += __shfl_xor(s, 8, 64);
                if (lr == 0) atomicAdd(&rsum[m], s);
            }
    }

    // publish: qg stores + rsum atomics -> L2, then release-increment
    __threadfence();
    __syncthreads();
    if (tid == 0)
        __hip_atomic_fetch_add(&done[xcd * 16 + mT], 1u,
                               __ATOMIC_RELEASE, __HIP_MEMORY_SCOPE_AGENT);

    // wait for all 4 producers of this m-strip (incl. self)
    if (tid == 0) {
        while (__hip_atomic_load(&done[xcd * 16 + mT],
                                 __ATOMIC_ACQUIRE, __HIP_MEMORY_SCOPE_AGENT) < 4u)
            __builtin_amdgcn_s_sleep(8);
    }
    __syncthreads();   // acquire's L1-invalidate ordered before consume reads

    // ---------------- CONSUME: gemm2 128x128 (same m-strip, d-slice q) --------
    {
        const int N = DIM_Z, K = DIM_G;
        int nBase = q * 128;
        f32x4 acc[4][4] = {};
        const u16* aSrc = qg + (size_t)(mBase + sRow) * K + cw * 8;
        const u16* bSrc = WTall + (size_t)b * DIM_Z * DIM_G
                                + (size_t)(nBase + sRow) * K + cw * 8;

        for (int kt = 0; kt < K; kt += BK) {
            __syncthreads();
#pragma unroll
            for (int r = 0; r < 4; ++r) {
                GLD16(aSrc + (size_t)r * 32 * K + kt, &As[(r * 256 + wid * 64) * 8]);
                GLD16(bSrc + (size_t)r * 32 * K + kt, &Bs[(r * 256 + wid * 64) * 8]);
            }
            __syncthreads();
#pragma unroll
            for (int ks = 0; ks < 2; ++ks) {
                bf16x8 af[4], bfr[4];
#pragma unroll
                for (int mi = 0; mi < 4; ++mi) {
                    int row = wm * 64 + mi * 16 + lr;
                    int cq  = (ks * 4 + lg) ^ (row & 7);
                    af[mi] = *(const bf16x8*)&As[row * BK + cq * 8];
                }
#pragma unroll
                for (int ni = 0; ni < 4; ++ni) {
                    int row = wn * 64 + ni * 16 + lr;
                    int cq  = (ks * 4 + lg) ^ (row & 7);
                    bfr[ni] = *(const bf16x8*)&Bs[row * BK + cq * 8];
                }
                __builtin_amdgcn_s_setprio(1);
#pragma unroll
                for (int mi = 0; mi < 4; ++mi)
#pragma unroll
                    for (int ni = 0; ni < 4; ++ni)
                        acc[mi][ni] = __builtin_amdgcn_mfma_f32_16x16x32_bf16(
                            af[mi], bfr[ni], acc[mi][ni], 0, 0, 0);
                __builtin_amdgcn_s_setprio(0);
            }
        }

        int mw = mBase + wm * 64, nw = nBase + wn * 64;
#pragma unroll
        for (int mi = 0; mi < 4; ++mi)
#pragma unroll
            for (int r = 0; r < 4; ++r) {
                int m = mw + mi * 16 + lg * 4 + r;
                float inv = 1.f / fmaxf(rsum[m], EPS);
#pragma unroll
                for (int ni = 0; ni < 4; ++ni)
                    __builtin_nontemporal_store(acc[mi][ni][r] * inv,
                        &out[(size_t)m * N + nw + ni * 16 + lr]);
            }
    }
}

extern "C" void kernel_launch(void* const* d_in, const int* in_sizes, int n_in,
                              void* d_out, int out_size, void* d_ws, size_t ws_size,
                              hipStream_t stream) {
    const float* qz    = (const float*)d_in[0];
    const int*   attr  = (const int*)d_in[1];
    const float* Wbase = (const float*)d_in[2];
    const float* emb   = (const float*)d_in[3];
    const float* Wu    = (const float*)d_in[4];
    const float* Wv    = (const float*)d_in[5];
    float* out = (float*)d_out;

    // workspace carve-up (all 256B aligned)
    char* ws = (char*)d_ws;
    size_t off = 0;
    auto alloc = [&](size_t bytes) -> void* {
        void* p = ws + off;
        off = (off + bytes + 255) & ~(size_t)255;
        return p;
    };
    float* u    = (float*)alloc((size_t)BATCH * DIM_G * 4);
    float* v    = (float*)alloc((size_t)BATCH * DIM_Z * 4);
    float* rsum = (float*)alloc((size_t)MTOT * 4);
    u32*   done = (u32*)  alloc(128 * 4);
    u16*   W    = (u16*)  alloc((size_t)BATCH * DIM_G * DIM_Z * 2);
    u16*   WT   = (u16*)  alloc((size_t)BATCH * DIM_G * DIM_Z * 2);
    u16*   qg   = (u16*)  alloc((size_t)MTOT * DIM_G * 2);
    if (off > ws_size) return;  // fail loudly (zero output) rather than corrupt

    uv_kernel<<<dim3(6, BATCH), dim3(256), 0, stream>>>(
        emb, attr, Wu, Wv, u, v, rsum, done);

    wpack_kernel<<<dim3(4096), dim3(32, 8), 0, stream>>>(Wbase, u, v, W, WT);

    // fused producer-consumer: 64 blocks/XCD x 8 = 512 blocks, all co-resident
    gemm_fused<<<dim3(512), dim3(256), 0, stream>>>(
        qz, W, WT, qg, rsum, out, done);
}

// Round 19
// 81.442 us; speedup vs baseline: 2.0783x; 2.0783x over previous
//
#include <hip/hip_runtime.h>
#include <hip/hip_bf16.h>

// Problem constants (from reference)
#define BATCH   8
#define MROWS   2048      // C*P per batch
#define MTOT    16384     // BATCH*MROWS
#define DIM_Z   512
#define DIM_G   1024
#define EDIM    128
#define EPS     1e-6f
#define BK      64        // K-step

typedef unsigned short u16;
typedef unsigned int   u32;
typedef __attribute__((ext_vector_type(8))) short bf16x8;
typedef __attribute__((ext_vector_type(4))) float f32x4;

// f32 -> bf16 round-to-nearest-even (bit trick; inputs are finite)
__device__ __forceinline__ u16 f2b(float f) {
    u32 x = __float_as_uint(f);
    u32 r = x + 0x7fffu + ((x >> 16) & 1u);
    return (u16)(r >> 16);
}

// packed f32 pair -> 2x bf16 in one u32 (RNE), single VALU inst on gfx950
__device__ __forceinline__ u32 cvtpk(float lo, float hi) {
    u32 r;
    asm("v_cvt_pk_bf16_f32 %0, %1, %2" : "=v"(r) : "v"(lo), "v"(hi));
    return r;
}

// async global->LDS, 16B per lane, dest = wave-uniform base + lane*16
#define GLD16(gsrc, ldst) __builtin_amdgcn_global_load_lds( \
    (const __attribute__((address_space(1))) unsigned int*)(gsrc), \
    (__attribute__((address_space(3))) unsigned int*)(ldst), 16, 0, 0)

// ---- kernel 1: u = a_emb @ Wu^T, v = a_emb @ Wv^T (coalesced); zero rsum ----
__global__ void uv_kernel(const float* __restrict__ emb, const int* __restrict__ idx,
                          const float* __restrict__ Wu, const float* __restrict__ Wv,
                          float* __restrict__ u, float* __restrict__ v,
                          float* __restrict__ rsum) {
    __shared__ float a[EDIM];
    int b = blockIdx.y;
    int t = threadIdx.x;
    if (blockIdx.x == 0)   // zero rsum slice for batch b (runs before GEMM1)
        for (int i = t; i < MROWS; i += 256) rsum[(size_t)b * MROWS + i] = 0.f;
    if (t < EDIM) a[t] = emb[(size_t)idx[b] * EDIM + t];
    __syncthreads();
    int tx = t & 31, ty = t >> 5;
    int oBase = blockIdx.x * 256;
    for (int o0 = 0; o0 < 256; o0 += 8) {
        int o = oBase + o0 + ty;
        const float* wrow = (o < DIM_G) ? (Wu + (size_t)o * EDIM)
                                        : (Wv + (size_t)(o - DIM_G) * EDIM);
        float s = 0.f;
#pragma unroll
        for (int q = 0; q < 4; ++q) s += a[q * 32 + tx] * wrow[q * 32 + tx];
        s += __shfl_xor(s, 1, 64);
        s += __shfl_xor(s, 2, 64);
        s += __shfl_xor(s, 4, 64);
        s += __shfl_xor(s, 8, 64);
        s += __shfl_xor(s, 16, 64);
        if (tx == 0) {
            if (o < DIM_G) u[b * DIM_G + o] = s;
            else           v[b * DIM_Z + (o - DIM_G)] = s;
        }
    }
}

// -- kernel 2: W[b,g,d] = W_base + u*v -> bf16 (+ transposed WT), b = h&7 --
// XCD-aligned so each batch's W/WT land dirty in the L2 of the XCD whose GEMM
// blocks (same b = xcd mapping) will read them.
__global__ void wpack_kernel(const float* __restrict__ Wbase,
                             const float* __restrict__ u, const float* __restrict__ v,
                             u16* __restrict__ W, u16* __restrict__ WT) {
    __shared__ u16 tile[32][33];
    int h = blockIdx.x;
    int b = h & 7, t8 = h >> 3;          // t8 in [0,512)
    int d0 = (t8 & 15) * 32, g0 = (t8 >> 4) * 32;
    int tx = threadIdx.x, ty = threadIdx.y;
    float vb = v[b * DIM_Z + d0 + tx];
#pragma unroll
    for (int j = 0; j < 4; ++j) {
        int g = g0 + ty + j * 8;
        u16 h16 = f2b(Wbase[(size_t)g * DIM_Z + d0 + tx] + u[b * DIM_G + g] * vb);
        W[((size_t)b * DIM_G + g) * DIM_Z + d0 + tx] = h16;
        tile[ty + j * 8][tx] = h16;
    }
    __syncthreads();
#pragma unroll
    for (int j = 0; j < 4; ++j)
        WT[((size_t)b * DIM_Z + d0 + ty + j * 8) * DIM_G + g0 + tx] =
            tile[tx][ty + j * 8];
}

// ---------- GEMM1 (FAT TILE): qg = relu(qz @ W[b]^T); rsum[m] = row-sum ----------
// 128m x 256n tile, 4 waves of 64x128 (acc 4x8) -> block-iterations halved and
// FLOP per staged LDS byte 1.37x (r17-proven: 84.7 -> 81.2). A = qz f32 fused
// (issue-early f32 loads, v_cvt_pk_bf16_f32, swizzled ds_write). B = W[b] via
// global_load_lds (source chunk pre-swizzled cw = c'^(row&7); reads same XOR).
// LDS 48 KB, LB(256,2). XCD decode: xcd = h&7 owns batch xcd's m-range.
// qg stored NORMAL (L2-hot for GEMM2 — r13 lesson).
__global__ __launch_bounds__(256, 2)
void gemm1(const float* __restrict__ qz, const u16* __restrict__ Wall,
           u16* __restrict__ qg, float* __restrict__ rsum) {
    const int N = DIM_G, K = DIM_Z;
    __shared__ u16 As[128 * BK];   // 16 KB
    __shared__ u16 Bs[256 * BK];   // 32 KB

    int h = blockIdx.x;
    int xcd = h & 7, idx = h >> 3;
    int tile = xcd * 64 + idx;               // 16 mT x 4 nT per XCD
    int mBase = (tile >> 2) * 128;
    int nBase = (tile & 3) * 256;
    int b = mBase >> 11;                      // == xcd

    int tid  = threadIdx.x;
    int lane = tid & 63, wid = tid >> 6;
    int wm = wid >> 1, wn = wid & 1;          // 2M x 2N fat waves
    int lr = lane & 15, lg = lane >> 4;

    f32x4 acc[4][8] = {};

    int sRow = tid >> 3;                      // 0..31
    int sC   = tid & 7;
    int cw   = sC ^ (sRow & 7);
    const float* aSrc = qz + (size_t)(mBase + sRow) * K + sC * 8;     // straight
    const u16*   bSrc = Wall + (size_t)b * DIM_G * DIM_Z
                             + (size_t)(nBase + sRow) * K + cw * 8;   // pre-swz

    for (int kt = 0; kt < K; kt += BK) {
        float4 alo[4], ahi[4];
#pragma unroll
        for (int r = 0; r < 4; ++r) {         // issue-early: no LDS hazard
            const float* g = aSrc + (size_t)r * 32 * K + kt;
            alo[r] = *(const float4*)g;
            ahi[r] = *(const float4*)(g + 4);
        }
        __syncthreads();   // previous tile's reads done before overwrite
#pragma unroll
        for (int r = 0; r < 8; ++r)           // B: 256 rows
            GLD16(bSrc + (size_t)r * 32 * K + kt, &Bs[(r * 256 + wid * 64) * 8]);
#pragma unroll
        for (int r = 0; r < 4; ++r) {         // packed cvt + swizzled ds_write
            uint4 q;
            q.x = cvtpk(alo[r].x, alo[r].y);
            q.y = cvtpk(alo[r].z, alo[r].w);
            q.z = cvtpk(ahi[r].x, ahi[r].y);
            q.w = cvtpk(ahi[r].z, ahi[r].w);
            *(uint4*)&As[(r * 32 + sRow) * BK + cw * 8] = q;
        }
        __syncthreads();   // tile landed
#pragma unroll
        for (int ks = 0; ks < 2; ++ks) {
            bf16x8 af[4], bfr[8];
#pragma unroll
            for (int mi = 0; mi < 4; ++mi) {
                int row = wm * 64 + mi * 16 + lr;
                int cq  = (ks * 4 + lg) ^ (row & 7);
                af[mi] = *(const bf16x8*)&As[row * BK + cq * 8];
            }
#pragma unroll
            for (int ni = 0; ni < 8; ++ni) {
                int row = wn * 128 + ni * 16 + lr;
                int cq  = (ks * 4 + lg) ^ (row & 7);
                bfr[ni] = *(const bf16x8*)&Bs[row * BK + cq * 8];
            }
            __builtin_amdgcn_s_setprio(1);
#pragma unroll
            for (int mi = 0; mi < 4; ++mi)
#pragma unroll
                for (int ni = 0; ni < 8; ++ni)
                    acc[mi][ni] = __builtin_amdgcn_mfma_f32_16x16x32_bf16(
                        af[mi], bfr[ni], acc[mi][ni], 0, 0, 0);
            __builtin_amdgcn_s_setprio(0);
        }
    }

    int mw = mBase + wm * 64, nw = nBase + wn * 128;
#pragma unroll
    for (int mi = 0; mi < 4; ++mi)
#pragma unroll
        for (int r = 0; r < 4; ++r) {
            int m = mw + mi * 16 + lg * 4 + r;
            float vals[8];
            float s = 0.f;
#pragma unroll
            for (int ni = 0; ni < 8; ++ni) {
                vals[ni] = fmaxf(acc[mi][ni][r], 0.f);
                s += vals[ni];
            }
#pragma unroll
            for (int ni = 0; ni < 8; ++ni)
                qg[(size_t)m * N + nw + ni * 16 + lr] = f2b(vals[ni]);
            s += __shfl_xor(s, 1, 64);
            s += __shfl_xor(s, 2, 64);
            s += __shfl_xor(s, 4, 64);
            s += __shfl_xor(s, 8, 64);
            if (lr == 0) atomicAdd(&rsum[m], s);
        }
}

// ---------------- GEMM2: out = (qg @ WT[b]^T) / max(rsum,eps) ----------------
// The champion ~24 µs structure (UNCHANGED): both operands via global_load_lds,
// 128x128, (256,4), per-XCD m-range matching GEMM1 (qg L2-hot), NT out store.
__global__ __launch_bounds__(256, 4)
void gemm2(const u16* __restrict__ qg, const u16* __restrict__ WTall,
           const float* __restrict__ rsum, float* __restrict__ out) {
    const int N = DIM_Z, K = DIM_G;
    __shared__ u16 As[128 * BK];   // 16 KB
    __shared__ u16 Bs[128 * BK];   // 16 KB

    int h = blockIdx.x;
    int xcd = h & 7, idx = h >> 3;
    int tile = xcd * 64 + idx;               // 16 mT x 4 nT per XCD
    int mBase = (tile >> 2) * 128;
    int nBase = (tile & 3) * 128;
    int b = mBase >> 11;                      // == xcd

    int tid  = threadIdx.x;
    int lane = tid & 63, wid = tid >> 6;
    int wm = wid >> 1, wn = wid & 1;
    int lr = lane & 15, lg = lane >> 4;

    f32x4 acc[4][4] = {};

    int sRow = tid >> 3;
    int cw   = (tid & 7) ^ (sRow & 7);
    const u16* aSrc = qg + (size_t)(mBase + sRow) * K + cw * 8;
    const u16* bSrc = WTall + (size_t)b * DIM_Z * DIM_G
                            + (size_t)(nBase + sRow) * K + cw * 8;

    for (int kt = 0; kt < K; kt += BK) {
        __syncthreads();
#pragma unroll
        for (int r = 0; r < 4; ++r) {
            GLD16(aSrc + (size_t)r * 32 * K + kt, &As[(r * 256 + wid * 64) * 8]);
            GLD16(bSrc + (size_t)r * 32 * K + kt, &Bs[(r * 256 + wid * 64) * 8]);
        }
        __syncthreads();
#pragma unroll
        for (int ks = 0; ks < 2; ++ks) {
            bf16x8 af[4], bfr[4];
#pragma unroll
            for (int mi = 0; mi < 4; ++mi) {
                int row = wm * 64 + mi * 16 + lr;
                int cq  = (ks * 4 + lg) ^ (row & 7);
                af[mi] = *(const bf16x8*)&As[row * BK + cq * 8];
            }
#pragma unroll
            for (int ni = 0; ni < 4; ++ni) {
                int row = wn * 64 + ni * 16 + lr;
                int cq  = (ks * 4 + lg) ^ (row & 7);
                bfr[ni] = *(const bf16x8*)&Bs[row * BK + cq * 8];
            }
            __builtin_amdgcn_s_setprio(1);
#pragma unroll
            for (int mi = 0; mi < 4; ++mi)
#pragma unroll
                for (int ni = 0; ni < 4; ++ni)
                    acc[mi][ni] = __builtin_amdgcn_mfma_f32_16x16x32_bf16(
                        af[mi], bfr[ni], acc[mi][ni], 0, 0, 0);
            __builtin_amdgcn_s_setprio(0);
        }
    }

    int mw = mBase + wm * 64, nw = nBase + wn * 64;
#pragma unroll
    for (int mi = 0; mi < 4; ++mi)
#pragma unroll
        for (int r = 0; r < 4; ++r) {
            int m = mw + mi * 16 + lg * 4 + r;
            float inv = 1.f / fmaxf(rsum[m], EPS);
#pragma unroll
            for (int ni = 0; ni < 4; ++ni)
                __builtin_nontemporal_store(acc[mi][ni][r] * inv,
                    &out[(size_t)m * N + nw + ni * 16 + lr]);
        }
}

extern "C" void kernel_launch(void* const* d_in, const int* in_sizes, int n_in,
                              void* d_out, int out_size, void* d_ws, size_t ws_size,
                              hipStream_t stream) {
    const float* qz    = (const float*)d_in[0];
    const int*   attr  = (const int*)d_in[1];
    const float* Wbase = (const float*)d_in[2];
    const float* emb   = (const float*)d_in[3];
    const float* Wu    = (const float*)d_in[4];
    const float* Wv    = (const float*)d_in[5];
    float* out = (float*)d_out;

    // workspace carve-up (all 256B aligned)
    char* ws = (char*)d_ws;
    size_t off = 0;
    auto alloc = [&](size_t bytes) -> void* {
        void* p = ws + off;
        off = (off + bytes + 255) & ~(size_t)255;
        return p;
    };
    float* u    = (float*)alloc((size_t)BATCH * DIM_G * 4);
    float* v    = (float*)alloc((size_t)BATCH * DIM_Z * 4);
    float* rsum = (float*)alloc((size_t)MTOT * 4);
    u16*   W    = (u16*)  alloc((size_t)BATCH * DIM_G * DIM_Z * 2);
    u16*   WT   = (u16*)  alloc((size_t)BATCH * DIM_G * DIM_Z * 2);
    u16*   qg   = (u16*)  alloc((size_t)MTOT * DIM_G * 2);
    if (off > ws_size) return;  // fail loudly (zero output) rather than corrupt

    uv_kernel<<<dim3(6, BATCH), dim3(256), 0, stream>>>(emb, attr, Wu, Wv, u, v, rsum);

    wpack_kernel<<<dim3(4096), dim3(32, 8), 0, stream>>>(Wbase, u, v, W, WT);

    // GEMM1 (fat 128x256): 16 mT x 4 nT x 8 xcd = 512 blocks
    gemm1<<<dim3(512), dim3(256), 0, stream>>>(qz, W, qg, rsum);

    // GEMM2 (champion 128x128): 16 mT x 4 nT x 8 xcd = 512 blocks
    gemm2<<<dim3(512), dim3(256), 0, stream>>>(qg, WT, rsum, out);
}

// Round 20
// 79.456 us; speedup vs baseline: 2.1302x; 1.0250x over previous
//
#include <hip/hip_runtime.h>
#include <hip/hip_bf16.h>

// Problem constants (from reference)
#define BATCH   8
#define MROWS   2048      // C*P per batch
#define MTOT    16384     // BATCH*MROWS
#define DIM_Z   512
#define DIM_G   1024
#define EDIM    128
#define EPS     1e-6f
#define BK      64        // K-step

typedef unsigned short u16;
typedef unsigned int   u32;
typedef __attribute__((ext_vector_type(8))) short bf16x8;
typedef __attribute__((ext_vector_type(4))) float f32x4;

// f32 -> bf16 round-to-nearest-even (bit trick; inputs are finite)
__device__ __forceinline__ u16 f2b(float f) {
    u32 x = __float_as_uint(f);
    u32 r = x + 0x7fffu + ((x >> 16) & 1u);
    return (u16)(r >> 16);
}

// packed f32 pair -> 2x bf16 in one u32 (RNE), single VALU inst on gfx950
__device__ __forceinline__ u32 cvtpk(float lo, float hi) {
    u32 r;
    asm("v_cvt_pk_bf16_f32 %0, %1, %2" : "=v"(r) : "v"(lo), "v"(hi));
    return r;
}

// async global->LDS, 16B per lane, dest = wave-uniform base + lane*16
#define GLD16(gsrc, ldst) __builtin_amdgcn_global_load_lds( \
    (const __attribute__((address_space(1))) unsigned int*)(gsrc), \
    (__attribute__((address_space(3))) unsigned int*)(ldst), 16, 0, 0)

#define MEMFENCE() asm volatile("" ::: "memory")

// ---- kernel 1: u = a_emb @ Wu^T, v = a_emb @ Wv^T (coalesced); zero rsum ----
__global__ void uv_kernel(const float* __restrict__ emb, const int* __restrict__ idx,
                          const float* __restrict__ Wu, const float* __restrict__ Wv,
                          float* __restrict__ u, float* __restrict__ v,
                          float* __restrict__ rsum) {
    __shared__ float a[EDIM];
    int b = blockIdx.y;
    int t = threadIdx.x;
    if (blockIdx.x == 0)   // zero rsum slice for batch b (runs before GEMM1)
        for (int i = t; i < MROWS; i += 256) rsum[(size_t)b * MROWS + i] = 0.f;
    if (t < EDIM) a[t] = emb[(size_t)idx[b] * EDIM + t];
    __syncthreads();
    int tx = t & 31, ty = t >> 5;
    int oBase = blockIdx.x * 256;
    for (int o0 = 0; o0 < 256; o0 += 8) {
        int o = oBase + o0 + ty;
        const float* wrow = (o < DIM_G) ? (Wu + (size_t)o * EDIM)
                                        : (Wv + (size_t)(o - DIM_G) * EDIM);
        float s = 0.f;
#pragma unroll
        for (int q = 0; q < 4; ++q) s += a[q * 32 + tx] * wrow[q * 32 + tx];
        s += __shfl_xor(s, 1, 64);
        s += __shfl_xor(s, 2, 64);
        s += __shfl_xor(s, 4, 64);
        s += __shfl_xor(s, 8, 64);
        s += __shfl_xor(s, 16, 64);
        if (tx == 0) {
            if (o < DIM_G) u[b * DIM_G + o] = s;
            else           v[b * DIM_Z + (o - DIM_G)] = s;
        }
    }
}

// -- kernel 2: W[b,g,d] = W_base + u*v -> bf16 (+ transposed WT), b = h&7 --
// XCD-aligned so each batch's W/WT land dirty in the L2 of the XCD whose GEMM
// blocks (same b = xcd mapping) will read them.
__global__ void wpack_kernel(const float* __restrict__ Wbase,
                             const float* __restrict__ u, const float* __restrict__ v,
                             u16* __restrict__ W, u16* __restrict__ WT) {
    __shared__ u16 tile[32][33];
    int h = blockIdx.x;
    int b = h & 7, t8 = h >> 3;          // t8 in [0,512)
    int d0 = (t8 & 15) * 32, g0 = (t8 >> 4) * 32;
    int tx = threadIdx.x, ty = threadIdx.y;
    float vb = v[b * DIM_Z + d0 + tx];
#pragma unroll
    for (int j = 0; j < 4; ++j) {
        int g = g0 + ty + j * 8;
        u16 h16 = f2b(Wbase[(size_t)g * DIM_Z + d0 + tx] + u[b * DIM_G + g] * vb);
        W[((size_t)b * DIM_G + g) * DIM_Z + d0 + tx] = h16;
        tile[ty + j * 8][tx] = h16;
    }
    __syncthreads();
#pragma unroll
    for (int j = 0; j < 4; ++j)
        WT[((size_t)b * DIM_Z + d0 + ty + j * 8) * DIM_G + g0 + tx] =
            tile[tx][ty + j * 8];
}

// ---------- GEMM1 (FAT TILE + counted-vmcnt pipeline) ----------
// r19 diagnosis: __syncthreads' implicit vmcnt(0) drained the just-issued qz
// f32 loads every iteration (full L3 latency exposed twice per iter; per-slot
// 6000 cy vs gemm2's 1800). Fix: raw s_barrier + counted waits + lead-1 A
// register prefetch. Per iter t (fully unrolled, static reg indexing):
//   s_barrier                         [compute(t-1) reads done; NO drain]
//   issue B(t) gld_lds (8)            [Bs overwrite safe: after barrier]
//   issue A(t+1) f32 -> regs (8)      [consumed next iter: full iter of cover]
//   cvt + ds_write A(t)               [compiler scoreboard waits A(t) only]
//   s_waitcnt vmcnt(8) lgkmcnt(0)     [B(t) landed; A(t+1) STAYS IN FLIGHT]
//   s_barrier                         [all waves' As/Bs writes visible]
//   ds_read + 32 MFMA/wave            [covers A(t+1) latency]
// Tile 128m x 256n, 4 waves of 64x128, BK=64, LDS 48 KB, LB(256,2).
// XCD decode: xcd = h&7 owns batch xcd's m-range. qg NORMAL store (L2-hot).
__global__ __launch_bounds__(256, 2)
void gemm1(const float* __restrict__ qz, const u16* __restrict__ Wall,
           u16* __restrict__ qg, float* __restrict__ rsum) {
    const int N = DIM_G, K = DIM_Z;
    __shared__ u16 As[128 * BK];   // 16 KB
    __shared__ u16 Bs[256 * BK];   // 32 KB

    int h = blockIdx.x;
    int xcd = h & 7, idx = h >> 3;
    int tile = xcd * 64 + idx;               // 16 mT x 4 nT per XCD
    int mBase = (tile >> 2) * 128;
    int nBase = (tile & 3) * 256;
    int b = mBase >> 11;                      // == xcd

    int tid  = threadIdx.x;
    int lane = tid & 63, wid = tid >> 6;
    int wm = wid >> 1, wn = wid & 1;          // 2M x 2N fat waves
    int lr = lane & 15, lg = lane >> 4;

    f32x4 acc[4][8] = {};

    int sRow = tid >> 3;                      // 0..31
    int sC   = tid & 7;
    int cw   = sC ^ (sRow & 7);
    const float* aSrc = qz + (size_t)(mBase + sRow) * K + sC * 8;     // straight
    const u16*   bSrc = Wall + (size_t)b * DIM_G * DIM_Z
                             + (size_t)(nBase + sRow) * K + cw * 8;   // pre-swz

    float4 alo[2][4], ahi[2][4];
    // prologue: issue A(0) loads (land under iter-0's B-issue + barrier)
#pragma unroll
    for (int r = 0; r < 4; ++r) {
        const float* g = aSrc + (size_t)r * 32 * K;
        alo[0][r] = *(const float4*)g;
        ahi[0][r] = *(const float4*)(g + 4);
    }

#pragma unroll
    for (int t = 0; t < 8; ++t) {             // K/BK == 8, fully unrolled
        const int cur = t & 1, nxt = cur ^ 1; // compile-time after unroll
        __builtin_amdgcn_s_barrier();         // compute(t-1) reads done; no drain
        MEMFENCE();
#pragma unroll
        for (int r = 0; r < 8; ++r)           // issue B(t): 256 rows
            GLD16(bSrc + (size_t)r * 32 * K + t * BK, &Bs[(r * 256 + wid * 64) * 8]);
        if (t < 7) {                          // issue A(t+1) -> regs (lead-1)
#pragma unroll
            for (int r = 0; r < 4; ++r) {
                const float* g = aSrc + (size_t)r * 32 * K + (t + 1) * BK;
                alo[nxt][r] = *(const float4*)g;
                ahi[nxt][r] = *(const float4*)(g + 4);
            }
        }
#pragma unroll
        for (int r = 0; r < 4; ++r) {         // cvt + swizzled ds_write A(t)
            uint4 q;
            q.x = cvtpk(alo[cur][r].x, alo[cur][r].y);
            q.y = cvtpk(alo[cur][r].z, alo[cur][r].w);
            q.z = cvtpk(ahi[cur][r].x, ahi[cur][r].y);
            q.w = cvtpk(ahi[cur][r].z, ahi[cur][r].w);
            *(uint4*)&As[(r * 32 + sRow) * BK + cw * 8] = q;
        }
        // B(t) landed + ds_writes done; A(t+1) (newest 8) stays in flight
        if (t < 7) asm volatile("s_waitcnt vmcnt(8) lgkmcnt(0)" ::: "memory");
        else       asm volatile("s_waitcnt vmcnt(0) lgkmcnt(0)" ::: "memory");
        __builtin_amdgcn_s_barrier();         // all waves' tile writes visible
        MEMFENCE();
#pragma unroll
        for (int ks = 0; ks < 2; ++ks) {
            bf16x8 af[4], bfr[8];
#pragma unroll
            for (int mi = 0; mi < 4; ++mi) {
                int row = wm * 64 + mi * 16 + lr;
                int cq  = (ks * 4 + lg) ^ (row & 7);
                af[mi] = *(const bf16x8*)&As[row * BK + cq * 8];
            }
#pragma unroll
            for (int ni = 0; ni < 8; ++ni) {
                int row = wn * 128 + ni * 16 + lr;
                int cq  = (ks * 4 + lg) ^ (row & 7);
                bfr[ni] = *(const bf16x8*)&Bs[row * BK + cq * 8];
            }
            __builtin_amdgcn_s_setprio(1);
#pragma unroll
            for (int mi = 0; mi < 4; ++mi)
#pragma unroll
                for (int ni = 0; ni < 8; ++ni)
                    acc[mi][ni] = __builtin_amdgcn_mfma_f32_16x16x32_bf16(
                        af[mi], bfr[ni], acc[mi][ni], 0, 0, 0);
            __builtin_amdgcn_s_setprio(0);
        }
        MEMFENCE();
    }

    int mw = mBase + wm * 64, nw = nBase + wn * 128;
#pragma unroll
    for (int mi = 0; mi < 4; ++mi)
#pragma unroll
        for (int r = 0; r < 4; ++r) {
            int m = mw + mi * 16 + lg * 4 + r;
            float vals[8];
            float s = 0.f;
#pragma unroll
            for (int ni = 0; ni < 8; ++ni) {
                vals[ni] = fmaxf(acc[mi][ni][r], 0.f);
                s += vals[ni];
            }
#pragma unroll
            for (int ni = 0; ni < 8; ++ni)
                qg[(size_t)m * N + nw + ni * 16 + lr] = f2b(vals[ni]);
            s += __shfl_xor(s, 1, 64);
            s += __shfl_xor(s, 2, 64);
            s += __shfl_xor(s, 4, 64);
            s += __shfl_xor(s, 8, 64);
            if (lr == 0) atomicAdd(&rsum[m], s);
        }
}

// ---------------- GEMM2: out = (qg @ WT[b]^T) / max(rsum,eps) ----------------
// The champion ~24 µs structure (UNCHANGED): both operands via global_load_lds,
// 128x128, (256,4), per-XCD m-range matching GEMM1 (qg L2-hot), NT out store.
__global__ __launch_bounds__(256, 4)
void gemm2(const u16* __restrict__ qg, const u16* __restrict__ WTall,
           const float* __restrict__ rsum, float* __restrict__ out) {
    const int N = DIM_Z, K = DIM_G;
    __shared__ u16 As[128 * BK];   // 16 KB
    __shared__ u16 Bs[128 * BK];   // 16 KB

    int h = blockIdx.x;
    int xcd = h & 7, idx = h >> 3;
    int tile = xcd * 64 + idx;               // 16 mT x 4 nT per XCD
    int mBase = (tile >> 2) * 128;
    int nBase = (tile & 3) * 128;
    int b = mBase >> 11;                      // == xcd

    int tid  = threadIdx.x;
    int lane = tid & 63, wid = tid >> 6;
    int wm = wid >> 1, wn = wid & 1;
    int lr = lane & 15, lg = lane >> 4;

    f32x4 acc[4][4] = {};

    int sRow = tid >> 3;
    int cw   = (tid & 7) ^ (sRow & 7);
    const u16* aSrc = qg + (size_t)(mBase + sRow) * K + cw * 8;
    const u16* bSrc = WTall + (size_t)b * DIM_Z * DIM_G
                            + (size_t)(nBase + sRow) * K + cw * 8;

    for (int kt = 0; kt < K; kt += BK) {
        __syncthreads();
#pragma unroll
        for (int r = 0; r < 4; ++r) {
            GLD16(aSrc + (size_t)r * 32 * K + kt, &As[(r * 256 + wid * 64) * 8]);
            GLD16(bSrc + (size_t)r * 32 * K + kt, &Bs[(r * 256 + wid * 64) * 8]);
        }
        __syncthreads();
#pragma unroll
        for (int ks = 0; ks < 2; ++ks) {
            bf16x8 af[4], bfr[4];
#pragma unroll
            for (int mi = 0; mi < 4; ++mi) {
                int row = wm * 64 + mi * 16 + lr;
                int cq  = (ks * 4 + lg) ^ (row & 7);
                af[mi] = *(const bf16x8*)&As[row * BK + cq * 8];
            }
#pragma unroll
            for (int ni = 0; ni < 4; ++ni) {
                int row = wn * 64 + ni * 16 + lr;
                int cq  = (ks * 4 + lg) ^ (row & 7);
                bfr[ni] = *(const bf16x8*)&Bs[row * BK + cq * 8];
            }
            __builtin_amdgcn_s_setprio(1);
#pragma unroll
            for (int mi = 0; mi < 4; ++mi)
#pragma unroll
                for (int ni = 0; ni < 4; ++ni)
                    acc[mi][ni] = __builtin_amdgcn_mfma_f32_16x16x32_bf16(
                        af[mi], bfr[ni], acc[mi][ni], 0, 0, 0);
            __builtin_amdgcn_s_setprio(0);
        }
    }

    int mw = mBase + wm * 64, nw = nBase + wn * 64;
#pragma unroll
    for (int mi = 0; mi < 4; ++mi)
#pragma unroll
        for (int r = 0; r < 4; ++r) {
            int m = mw + mi * 16 + lg * 4 + r;
            float inv = 1.f / fmaxf(rsum[m], EPS);
#pragma unroll
            for (int ni = 0; ni < 4; ++ni)
                __builtin_nontemporal_store(acc[mi][ni][r] * inv,
                    &out[(size_t)m * N + nw + ni * 16 + lr]);
        }
}

extern "C" void kernel_launch(void* const* d_in, const int* in_sizes, int n_in,
                              void* d_out, int out_size, void* d_ws, size_t ws_size,
                              hipStream_t stream) {
    const float* qz    = (const float*)d_in[0];
    const int*   attr  = (const int*)d_in[1];
    const float* Wbase = (const float*)d_in[2];
    const float* emb   = (const float*)d_in[3];
    const float* Wu    = (const float*)d_in[4];
    const float* Wv    = (const float*)d_in[5];
    float* out = (float*)d_out;

    // workspace carve-up (all 256B aligned)
    char* ws = (char*)d_ws;
    size_t off = 0;
    auto alloc = [&](size_t bytes) -> void* {
        void* p = ws + off;
        off = (off + bytes + 255) & ~(size_t)255;
        return p;
    };
    float* u    = (float*)alloc((size_t)BATCH * DIM_G * 4);
    float* v    = (float*)alloc((size_t)BATCH * DIM_Z * 4);
    float* rsum = (float*)alloc((size_t)MTOT * 4);
    u16*   W    = (u16*)  alloc((size_t)BATCH * DIM_G * DIM_Z * 2);
    u16*   WT   = (u16*)  alloc((size_t)BATCH * DIM_G * DIM_Z * 2);
    u16*   qg   = (u16*)  alloc((size_t)MTOT * DIM_G * 2);
    if (off > ws_size) return;  // fail loudly (zero output) rather than corrupt

    uv_kernel<<<dim3(6, BATCH), dim3(256), 0, stream>>>(emb, attr, Wu, Wv, u, v, rsum);

    wpack_kernel<<<dim3(4096), dim3(32, 8), 0, stream>>>(Wbase, u, v, W, WT);

    // GEMM1 (fat 128x256, counted-vmcnt pipeline): 16 mT x 4 nT x 8 xcd = 512
    gemm1<<<dim3(512), dim3(256), 0, stream>>>(qz, W, qg, rsum);

    // GEMM2 (champion 128x128): 16 mT x 4 nT x 8 xcd = 512 blocks
    gemm2<<<dim3(512), dim3(256), 0, stream>>>(qg, WT, rsum, out);
}

// Round 21
// 67.921 us; speedup vs baseline: 2.4920x; 1.1698x over previous
//
#include <hip/hip_runtime.h>
#include <hip/hip_bf16.h>

// Problem constants (from reference)
#define BATCH   8
#define MROWS   2048      // C*P per batch
#define MTOT    16384     // BATCH*MROWS
#define DIM_Z   512
#define DIM_G   1024
#define EDIM    128
#define EPS     1e-6f
#define BK      64        // K-step

typedef unsigned short u16;
typedef unsigned int   u32;
typedef __attribute__((ext_vector_type(8))) short bf16x8;
typedef __attribute__((ext_vector_type(4))) float f32x4;

// f32 -> bf16 round-to-nearest-even (bit trick; inputs are finite)
__device__ __forceinline__ u16 f2b(float f) {
    u32 x = __float_as_uint(f);
    u32 r = x + 0x7fffu + ((x >> 16) & 1u);
    return (u16)(r >> 16);
}

// packed f32 pair -> 2x bf16 in one u32 (RNE), single VALU inst on gfx950
__device__ __forceinline__ u32 cvtpk(float lo, float hi) {
    u32 r;
    asm("v_cvt_pk_bf16_f32 %0, %1, %2" : "=v"(r) : "v"(lo), "v"(hi));
    return r;
}

// async global->LDS, 16B per lane, dest = wave-uniform base + lane*16
#define GLD16(gsrc, ldst) __builtin_amdgcn_global_load_lds( \
    (const __attribute__((address_space(1))) unsigned int*)(gsrc), \
    (__attribute__((address_space(3))) unsigned int*)(ldst), 16, 0, 0)

#define MEMFENCE() asm volatile("" ::: "memory")

// ---- kernel 1 (FUSED uv+wpack): W[b] = W_base + u_b (x) v_b -> bf16 + WT ----
// 512 blocks (16 d-tiles x 32 g-tiles), all 8 batches per block (Wbase tile
// read ONCE into regs). Per batch: emb row -> LDS; the 64 u/v slice values
// this tile needs are 64 length-128 dots (4 lanes/output, shfl reduce);
// then W/WT tiles as before. rsum zeroing folded into first 64 blocks.
// Replaces the separate uv_kernel (one dispatch + gap saved).
__global__ void wpack_uv(const float* __restrict__ Wbase,
                         const float* __restrict__ emb, const int* __restrict__ idx,
                         const float* __restrict__ Wu, const float* __restrict__ Wv,
                         u16* __restrict__ W, u16* __restrict__ WT,
                         float* __restrict__ rsum) {
    __shared__ float a_sh[EDIM];
    __shared__ float us[32], vs[32];
    __shared__ u16 tile[32][33];

    int h = blockIdx.x;
    int d0 = (h & 15) * 32, g0 = (h >> 4) * 32;
    int tx = threadIdx.x, ty = threadIdx.y;
    int tid = ty * 32 + tx;

    if (h < 64)   // zero rsum (runs before gemm1 in stream order)
        for (int i = tid; i < 256; i += 256) rsum[h * 256 + i] = 0.f;

    // Wbase tile -> regs (once; reused by all 8 batches)
    float base[4];
#pragma unroll
    for (int j = 0; j < 4; ++j)
        base[j] = Wbase[(size_t)(g0 + ty + j * 8) * DIM_Z + d0 + tx];

    int slot = tid >> 2, q = tid & 3;   // 64 outputs, 4 lanes each
    const float* wrow = (slot < 32) ? (Wu + (size_t)(g0 + slot) * EDIM)
                                    : (Wv + (size_t)(d0 + slot - 32) * EDIM);

    for (int b = 0; b < BATCH; ++b) {
        if (tid < EDIM) a_sh[tid] = emb[(size_t)idx[b] * EDIM + tid];
        __syncthreads();
        float s = 0.f;
#pragma unroll
        for (int i = 0; i < 32; ++i) s += a_sh[q * 32 + i] * wrow[q * 32 + i];
        s += __shfl_xor(s, 1, 64);
        s += __shfl_xor(s, 2, 64);
        if (q == 0) {
            if (slot < 32) us[slot] = s;
            else           vs[slot - 32] = s;
        }
        __syncthreads();
        float vb = vs[tx];
#pragma unroll
        for (int j = 0; j < 4; ++j) {
            int g = g0 + ty + j * 8;
            u16 h16 = f2b(base[j] + us[ty + j * 8] * vb);
            W[((size_t)b * DIM_G + g) * DIM_Z + d0 + tx] = h16;
            tile[ty + j * 8][tx] = h16;
        }
        __syncthreads();
#pragma unroll
        for (int j = 0; j < 4; ++j)
            WT[((size_t)b * DIM_Z + d0 + ty + j * 8) * DIM_G + g0 + tx] =
                tile[tx][ty + j * 8];
        __syncthreads();   // WAR on tile/a_sh before next batch
    }
}

// ---------- GEMM1 (FAT TILE + counted-vmcnt pipeline) — r20 champion ----------
// Per iter t (fully unrolled, static reg indexing):
//   s_barrier                         [compute(t-1) reads done; NO drain]
//   issue B(t) gld_lds (8)            [Bs overwrite safe: after barrier]
//   issue A(t+1) f32 -> regs (8)      [consumed next iter: full iter of cover]
//   cvt + ds_write A(t)
//   s_waitcnt vmcnt(8) lgkmcnt(0)     [B(t) landed; A(t+1) STAYS IN FLIGHT]
//   s_barrier -> ds_read + 32 MFMA/wave
// Tile 128m x 256n, 4 waves of 64x128, BK=64, LDS 48 KB, LB(256,2).
// XCD decode: xcd = h&7 owns batch xcd's m-range. qg NORMAL store (L2-hot).
__global__ __launch_bounds__(256, 2)
void gemm1(const float* __restrict__ qz, const u16* __restrict__ Wall,
           u16* __restrict__ qg, float* __restrict__ rsum) {
    const int N = DIM_G, K = DIM_Z;
    __shared__ u16 As[128 * BK];   // 16 KB
    __shared__ u16 Bs[256 * BK];   // 32 KB

    int h = blockIdx.x;
    int xcd = h & 7, idx = h >> 3;
    int tile = xcd * 64 + idx;               // 16 mT x 4 nT per XCD
    int mBase = (tile >> 2) * 128;
    int nBase = (tile & 3) * 256;
    int b = mBase >> 11;                      // == xcd

    int tid  = threadIdx.x;
    int lane = tid & 63, wid = tid >> 6;
    int wm = wid >> 1, wn = wid & 1;          // 2M x 2N fat waves
    int lr = lane & 15, lg = lane >> 4;

    f32x4 acc[4][8] = {};

    int sRow = tid >> 3;                      // 0..31
    int sC   = tid & 7;
    int cw   = sC ^ (sRow & 7);
    const float* aSrc = qz + (size_t)(mBase + sRow) * K + sC * 8;     // straight
    const u16*   bSrc = Wall + (size_t)b * DIM_G * DIM_Z
                             + (size_t)(nBase + sRow) * K + cw * 8;   // pre-swz

    float4 alo[2][4], ahi[2][4];
    // prologue: issue A(0) loads (land under iter-0's B-issue + barrier)
#pragma unroll
    for (int r = 0; r < 4; ++r) {
        const float* g = aSrc + (size_t)r * 32 * K;
        alo[0][r] = *(const float4*)g;
        ahi[0][r] = *(const float4*)(g + 4);
    }

#pragma unroll
    for (int t = 0; t < 8; ++t) {             // K/BK == 8, fully unrolled
        const int cur = t & 1, nxt = cur ^ 1; // compile-time after unroll
        __builtin_amdgcn_s_barrier();         // compute(t-1) reads done; no drain
        MEMFENCE();
#pragma unroll
        for (int r = 0; r < 8; ++r)           // issue B(t): 256 rows
            GLD16(bSrc + (size_t)r * 32 * K + t * BK, &Bs[(r * 256 + wid * 64) * 8]);
        if (t < 7) {                          // issue A(t+1) -> regs (lead-1)
#pragma unroll
            for (int r = 0; r < 4; ++r) {
                const float* g = aSrc + (size_t)r * 32 * K + (t + 1) * BK;
                alo[nxt][r] = *(const float4*)g;
                ahi[nxt][r] = *(const float4*)(g + 4);
            }
        }
#pragma unroll
        for (int r = 0; r < 4; ++r) {         // cvt + swizzled ds_write A(t)
            uint4 q;
            q.x = cvtpk(alo[cur][r].x, alo[cur][r].y);
            q.y = cvtpk(alo[cur][r].z, alo[cur][r].w);
            q.z = cvtpk(ahi[cur][r].x, ahi[cur][r].y);
            q.w = cvtpk(ahi[cur][r].z, ahi[cur][r].w);
            *(uint4*)&As[(r * 32 + sRow) * BK + cw * 8] = q;
        }
        // B(t) landed + ds_writes done; A(t+1) (newest 8) stays in flight
        if (t < 7) asm volatile("s_waitcnt vmcnt(8) lgkmcnt(0)" ::: "memory");
        else       asm volatile("s_waitcnt vmcnt(0) lgkmcnt(0)" ::: "memory");
        __builtin_amdgcn_s_barrier();         // all waves' tile writes visible
        MEMFENCE();
#pragma unroll
        for (int ks = 0; ks < 2; ++ks) {
            bf16x8 af[4], bfr[8];
#pragma unroll
            for (int mi = 0; mi < 4; ++mi) {
                int row = wm * 64 + mi * 16 + lr;
                int cq  = (ks * 4 + lg) ^ (row & 7);
                af[mi] = *(const bf16x8*)&As[row * BK + cq * 8];
            }
#pragma unroll
            for (int ni = 0; ni < 8; ++ni) {
                int row = wn * 128 + ni * 16 + lr;
                int cq  = (ks * 4 + lg) ^ (row & 7);
                bfr[ni] = *(const bf16x8*)&Bs[row * BK + cq * 8];
            }
            __builtin_amdgcn_s_setprio(1);
#pragma unroll
            for (int mi = 0; mi < 4; ++mi)
#pragma unroll
                for (int ni = 0; ni < 8; ++ni)
                    acc[mi][ni] = __builtin_amdgcn_mfma_f32_16x16x32_bf16(
                        af[mi], bfr[ni], acc[mi][ni], 0, 0, 0);
            __builtin_amdgcn_s_setprio(0);
        }
        MEMFENCE();
    }

    int mw = mBase + wm * 64, nw = nBase + wn * 128;
#pragma unroll
    for (int mi = 0; mi < 4; ++mi)
#pragma unroll
        for (int r = 0; r < 4; ++r) {
            int m = mw + mi * 16 + lg * 4 + r;
            float vals[8];
            float s = 0.f;
#pragma unroll
            for (int ni = 0; ni < 8; ++ni) {
                vals[ni] = fmaxf(acc[mi][ni][r], 0.f);
                s += vals[ni];
            }
#pragma unroll
            for (int ni = 0; ni < 8; ++ni)
                qg[(size_t)m * N + nw + ni * 16 + lr] = f2b(vals[ni]);
            s += __shfl_xor(s, 1, 64);
            s += __shfl_xor(s, 2, 64);
            s += __shfl_xor(s, 4, 64);
            s += __shfl_xor(s, 8, 64);
            if (lr == 0) atomicAdd(&rsum[m], s);
        }
}

// ---------------- GEMM2: out = (qg @ WT[b]^T) / max(rsum,eps) ----------------
// The champion ~24 µs structure (UNCHANGED): both operands via global_load_lds,
// 128x128, (256,4), per-XCD m-range matching GEMM1 (qg L2-hot), NT out store.
__global__ __launch_bounds__(256, 4)
void gemm2(const u16* __restrict__ qg, const u16* __restrict__ WTall,
           const float* __restrict__ rsum, float* __restrict__ out) {
    const int N = DIM_Z, K = DIM_G;
    __shared__ u16 As[128 * BK];   // 16 KB
    __shared__ u16 Bs[128 * BK];   // 16 KB

    int h = blockIdx.x;
    int xcd = h & 7, idx = h >> 3;
    int tile = xcd * 64 + idx;               // 16 mT x 4 nT per XCD
    int mBase = (tile >> 2) * 128;
    int nBase = (tile & 3) * 128;
    int b = mBase >> 11;                      // == xcd

    int tid  = threadIdx.x;
    int lane = tid & 63, wid = tid >> 6;
    int wm = wid >> 1, wn = wid & 1;
    int lr = lane & 15, lg = lane >> 4;

    f32x4 acc[4][4] = {};

    int sRow = tid >> 3;
    int cw   = (tid & 7) ^ (sRow & 7);
    const u16* aSrc = qg + (size_t)(mBase + sRow) * K + cw * 8;
    const u16* bSrc = WTall + (size_t)b * DIM_Z * DIM_G
                            + (size_t)(nBase + sRow) * K + cw * 8;

    for (int kt = 0; kt < K; kt += BK) {
        __syncthreads();
#pragma unroll
        for (int r = 0; r < 4; ++r) {
            GLD16(aSrc + (size_t)r * 32 * K + kt, &As[(r * 256 + wid * 64) * 8]);
            GLD16(bSrc + (size_t)r * 32 * K + kt, &Bs[(r * 256 + wid * 64) * 8]);
        }
        __syncthreads();
#pragma unroll
        for (int ks = 0; ks < 2; ++ks) {
            bf16x8 af[4], bfr[4];
#pragma unroll
            for (int mi = 0; mi < 4; ++mi) {
                int row = wm * 64 + mi * 16 + lr;
                int cq  = (ks * 4 + lg) ^ (row & 7);
                af[mi] = *(const bf16x8*)&As[row * BK + cq * 8];
            }
#pragma unroll
            for (int ni = 0; ni < 4; ++ni) {
                int row = wn * 64 + ni * 16 + lr;
                int cq  = (ks * 4 + lg) ^ (row & 7);
                bfr[ni] = *(const bf16x8*)&Bs[row * BK + cq * 8];
            }
            __builtin_amdgcn_s_setprio(1);
#pragma unroll
            for (int mi = 0; mi < 4; ++mi)
#pragma unroll
                for (int ni = 0; ni < 4; ++ni)
                    acc[mi][ni] = __builtin_amdgcn_mfma_f32_16x16x32_bf16(
                        af[mi], bfr[ni], acc[mi][ni], 0, 0, 0);
            __builtin_amdgcn_s_setprio(0);
        }
    }

    int mw = mBase + wm * 64, nw = nBase + wn * 64;
#pragma unroll
    for (int mi = 0; mi < 4; ++mi)
#pragma unroll
        for (int r = 0; r < 4; ++r) {
            int m = mw + mi * 16 + lg * 4 + r;
            float inv = 1.f / fmaxf(rsum[m], EPS);
#pragma unroll
            for (int ni = 0; ni < 4; ++ni)
                __builtin_nontemporal_store(acc[mi][ni][r] * inv,
                    &out[(size_t)m * N + nw + ni * 16 + lr]);
        }
}

extern "C" void kernel_launch(void* const* d_in, const int* in_sizes, int n_in,
                              void* d_out, int out_size, void* d_ws, size_t ws_size,
                              hipStream_t stream) {
    const float* qz    = (const float*)d_in[0];
    const int*   attr  = (const int*)d_in[1];
    const float* Wbase = (const float*)d_in[2];
    const float* emb   = (const float*)d_in[3];
    const float* Wu    = (const float*)d_in[4];
    const float* Wv    = (const float*)d_in[5];
    float* out = (float*)d_out;

    // workspace carve-up (all 256B aligned)
    char* ws = (char*)d_ws;
    size_t off = 0;
    auto alloc = [&](size_t bytes) -> void* {
        void* p = ws + off;
        off = (off + bytes + 255) & ~(size_t)255;
        return p;
    };
    float* rsum = (float*)alloc((size_t)MTOT * 4);
    u16*   W    = (u16*)  alloc((size_t)BATCH * DIM_G * DIM_Z * 2);
    u16*   WT   = (u16*)  alloc((size_t)BATCH * DIM_G * DIM_Z * 2);
    u16*   qg   = (u16*)  alloc((size_t)MTOT * DIM_G * 2);
    if (off > ws_size) return;  // fail loudly (zero output) rather than corrupt

    // fused uv+wpack: 512 blocks (16 d x 32 g), all batches per block
    wpack_uv<<<dim3(512), dim3(32, 8), 0, stream>>>(
        Wbase, emb, attr, Wu, Wv, W, WT, rsum);

    // GEMM1 (fat 128x256, counted-vmcnt pipeline): 16 mT x 4 nT x 8 xcd = 512
    gemm1<<<dim3(512), dim3(256), 0, stream>>>(qz, W, qg, rsum);

    // GEMM2 (champion 128x128): 16 mT x 4 nT x 8 xcd = 512 blocks
    gemm2<<<dim3(512), dim3(256), 0, stream>>>(qg, WT, rsum, out);
}